// Round 1
// baseline (317.594 us; speedup 1.0000x reference)
//
#include <hip/hip_runtime.h>

#define SS 8
#define NN 5000
#define DD 128
#define RB 10        // rows per block
#define JS 5         // column splits across blocks
#define JT 256       // tile columns
#define NT 20        // ceil(5000/256)
#define QSTRIDE 260  // LDS row stride (floats), 16B-aligned

// Kernel 1: out1[i,d] += sum_j ( (sum_s theta[s]*T[s,i,j]) * a[i,j] ) * x[j,d]
__global__ __launch_bounds__(256, 4)
void diffuse_spmm(const float* __restrict__ theta,
                  const float* __restrict__ T,
                  const float* __restrict__ x,
                  const float* __restrict__ a,
                  float* __restrict__ out1)
{
    __shared__ float qv[RB * QSTRIDE];
    const int t   = threadIdx.x;
    const int bid = blockIdx.x;
    const int rg  = bid / JS;
    const int js  = bid % JS;
    const int i0  = rg * RB;

    float th[SS];
#pragma unroll
    for (int s = 0; s < SS; ++s) th[s] = theta[s];

    const int slot = t & 31;   // d-slot: d0 = slot*4
    const int h    = t >> 5;   // j-subgroup 0..7
    const int d0   = slot << 2;

    float acc[RB][4];
#pragma unroll
    for (int r = 0; r < RB; ++r)
#pragma unroll
        for (int c = 0; c < 4; ++c) acc[r][c] = 0.0f;

    for (int k = 0; k < NT / JS; ++k) {
        const int tt = js + k * JS;
        const int j0 = tt * JT;

        __syncthreads();  // qv free from previous phase B
        // ---- Phase A: build qv[r][0..255] for this tile (coalesced streams) ----
        for (int it = 0; it < 3; ++it) {
            int item = it * 256 + t;
            if (item < RB * 64) {
                int r = item >> 6;
                int q = item & 63;
                int j = j0 + (q << 2);
                if (j < NN) {
                    size_t off = (size_t)(i0 + r) * NN + j;
                    float4 a4 = *(const float4*)(a + off);
                    float sx = 0.f, sy = 0.f, sz = 0.f, sw = 0.f;
#pragma unroll
                    for (int s = 0; s < SS; ++s) {
                        float4 t4 = *(const float4*)(T + (size_t)s * (size_t)NN * (size_t)NN + off);
                        sx += th[s] * t4.x; sy += th[s] * t4.y;
                        sz += th[s] * t4.z; sw += th[s] * t4.w;
                    }
                    float4 q4;
                    q4.x = a4.x * sx; q4.y = a4.y * sy;
                    q4.z = a4.z * sz; q4.w = a4.w * sw;
                    *(float4*)&qv[r * QSTRIDE + (q << 2)] = q4;
                }
            }
        }
        __syncthreads();

        // ---- Phase B: acc[r][c] += qv[r][j] * x[j][d0+c] ----
        for (int qq = 0; qq < 8; ++qq) {
            int jj = (h << 5) + (qq << 2);
            int j  = j0 + jj;
            if (j < NN) {   // j%4==0 and NN%4==0 => all 4 j's valid
                float xv[4][4];
#pragma unroll
                for (int jo = 0; jo < 4; ++jo) {
                    float4 xr = *(const float4*)(x + (size_t)(j + jo) * DD + d0);
                    xv[jo][0] = xr.x; xv[jo][1] = xr.y;
                    xv[jo][2] = xr.z; xv[jo][3] = xr.w;
                }
#pragma unroll
                for (int r = 0; r < RB; ++r) {
                    float4 q4 = *(float4*)&qv[r * QSTRIDE + jj];
                    float qa[4] = {q4.x, q4.y, q4.z, q4.w};
#pragma unroll
                    for (int jo = 0; jo < 4; ++jo)
#pragma unroll
                        for (int c = 0; c < 4; ++c)
                            acc[r][c] += qa[jo] * xv[jo][c];
                }
            }
        }
    }

    // reduce the h/h+1 pair inside each wave, then one atomic set per half-wave
#pragma unroll
    for (int r = 0; r < RB; ++r)
#pragma unroll
        for (int c = 0; c < 4; ++c)
            acc[r][c] += __shfl_xor(acc[r][c], 32);

    if ((t & 63) < 32) {
#pragma unroll
        for (int r = 0; r < RB; ++r)
#pragma unroll
            for (int c = 0; c < 4; ++c)
                atomicAdd(out1 + (size_t)(i0 + r) * DD + d0 + c, acc[r][c]);
    }
}

// Kernel 2 (in-place on out): out[i,:] = PReLU(out[i,:]) @ W^T + b
__global__ __launch_bounds__(256, 2)
void prelu_linear(const float* __restrict__ alpha,
                  const float* __restrict__ W,
                  const float* __restrict__ b,
                  float* __restrict__ out)
{
    __shared__ float Wt[128 * 129];  // transposed W, padded
    __shared__ float p[16 * 128];    // PReLU'd rows
    const int t  = threadIdx.x;
    const int i0 = blockIdx.x * 16;

    // load W (row-major [d][k]) transposed into Wt[k][d]
#pragma unroll
    for (int it = 0; it < 16; ++it) {
        int f = (it * 256 + t) * 4;       // flat = d*128 + k
        int d = f >> 7;
        int kk = f & 127;
        float4 w4 = *(const float4*)(W + f);
        Wt[(kk + 0) * 129 + d] = w4.x;
        Wt[(kk + 1) * 129 + d] = w4.y;
        Wt[(kk + 2) * 129 + d] = w4.z;
        Wt[(kk + 3) * 129 + d] = w4.w;
    }

    const int nval = (NN - i0 < 16 ? NN - i0 : 16) * 128;
    for (int it = 0; it < 2; ++it) {
        int f = (it * 256 + t) * 4;
        if (f < nval) {
            float4 v = *(const float4*)(out + (size_t)i0 * DD + f);
            float pv[4] = {v.x, v.y, v.z, v.w};
#pragma unroll
            for (int c = 0; c < 4; ++c) {
                float al = alpha[(f + c) & 127];
                p[f + c] = pv[c] >= 0.f ? pv[c] : al * pv[c];
            }
        }
    }
    __syncthreads();

    const int d  = t & 127;
    const int rg = t >> 7;
    const float bv = b[d];
    float acc[8];
#pragma unroll
    for (int ri = 0; ri < 8; ++ri) acc[ri] = 0.f;
    for (int k = 0; k < 128; ++k) {
        float w = Wt[k * 129 + d];
#pragma unroll
        for (int ri = 0; ri < 8; ++ri)
            acc[ri] += p[(rg * 8 + ri) * 128 + k] * w;
    }
#pragma unroll
    for (int ri = 0; ri < 8; ++ri) {
        int row = i0 + rg * 8 + ri;
        if (row < NN) out[(size_t)row * DD + d] = acc[ri] + bv;
    }
}

extern "C" void kernel_launch(void* const* d_in, const int* in_sizes, int n_in,
                              void* d_out, int out_size, void* d_ws, size_t ws_size,
                              hipStream_t stream) {
    const float* theta = (const float*)d_in[0];
    const float* T     = (const float*)d_in[1];
    const float* x     = (const float*)d_in[2];
    const float* a     = (const float*)d_in[3];
    const float* alpha = (const float*)d_in[4];
    const float* W     = (const float*)d_in[5];
    const float* b     = (const float*)d_in[6];
    float* out = (float*)d_out;

    // out is the accumulator for kernel 1 -> must be zeroed every call
    hipMemsetAsync(out, 0, (size_t)NN * DD * sizeof(float), stream);

    dim3 blk(256);
    dim3 g1((NN / RB) * JS);              // 500 row-groups * 5 column-splits = 2500
    diffuse_spmm<<<g1, blk, 0, stream>>>(theta, T, x, a, out);

    dim3 g2((NN + 15) / 16);              // 313
    prelu_linear<<<g2, blk, 0, stream>>>(alpha, W, b, out);
}

// Round 2
// 244.679 us; speedup vs baseline: 1.2980x; 1.2980x over previous
//
#include <hip/hip_runtime.h>

#define SS 8
#define NN 5000
#define NNSQ 25000000
#define DD 128
#define RB 8          // rows per block
#define JS 4          // column splits (partials)
#define JT 128        // tile columns
#define NT 40         // tiles total (last tile = 8 cols)
#define TPB 10        // tiles per block = NT/JS
#define QS 132        // qv row stride (floats)
#define RG 625        // row groups = NN/RB

typedef float f4 __attribute__((ext_vector_type(4)));

// Kernel 1: partial[js][i][d] = sum_{j in js-chunk} ((sum_s theta[s]*T[s,i,j]) * a[i,j]) * x[j,d]
__global__ __launch_bounds__(256, 4)
void diffuse_spmm(const float* __restrict__ theta,
                  const float* __restrict__ Tm,
                  const float* __restrict__ x,
                  const float* __restrict__ am,
                  float* __restrict__ ws)
{
    __shared__ float qv[2][RB * QS];       // double-buffered q tile
    __shared__ float red[3 * RB * 128];    // cross-wave reduction buffer

    const int t  = threadIdx.x;
    const int rg = blockIdx.x % RG;
    const int js = blockIdx.x / RG;
    const int i0 = rg * RB;
    const int tile0 = js * TPB;

    // Phase A mapping: 1 item/thread (8 rows x 32 quads)
    const int ar = t >> 5;            // row 0..7
    const int aj = (t & 31) << 2;     // col offset 0..124
    // Phase B mapping
    const int slot = t & 31;          // d-group
    const int h    = t >> 5;          // j-subgroup 0..7 (16 cols each)
    const int d0   = slot << 2;

    f4 sa;
    f4 st[SS];
    bool svalid = false;

    auto stage = [&](int tt) {
        int j = tt * JT + aj;
        svalid = (j < NN);
        if (svalid) {
            size_t off = (size_t)(i0 + ar) * NN + j;
            sa = __builtin_nontemporal_load((const f4*)(am + off));
#pragma unroll
            for (int s = 0; s < SS; ++s)
                st[s] = __builtin_nontemporal_load((const f4*)(Tm + (size_t)s * NNSQ + off));
        }
    };

    auto qwrite = [&](int nb) {
        f4 q;
        if (svalid) {
            f4 ssum = st[0] * theta[0];
#pragma unroll
            for (int s = 1; s < SS; ++s) ssum += st[s] * theta[s];
            q = sa * ssum;
        } else {
            q = (f4)(0.0f);
        }
        *(f4*)&qv[nb][ar * QS + aj] = q;
    };

    f4 acc[RB];
#pragma unroll
    for (int r = 0; r < RB; ++r) acc[r] = (f4)(0.0f);

    // prologue: stage + publish tile 0
    stage(tile0);
    qwrite(0);
    __syncthreads();

    int cur = 0;
    for (int k = 0; k < TPB; ++k) {
        // issue next tile's global loads FIRST -> in flight during phase B
        if (k + 1 < TPB) stage(tile0 + k + 1);

        // Phase B: acc[r] += qv[r][j] * x[j][d0..d0+3]
        const int j0 = (tile0 + k) * JT;
#pragma unroll
        for (int qq = 0; qq < 4; ++qq) {
            const int jj = (h << 4) + (qq << 2);
            const int j  = j0 + jj;
            if (j < NN) {
                const float* xp = x + (size_t)j * DD + d0;
                f4 xv0 = *(const f4*)(xp);
                f4 xv1 = *(const f4*)(xp + DD);
                f4 xv2 = *(const f4*)(xp + 2 * DD);
                f4 xv3 = *(const f4*)(xp + 3 * DD);
#pragma unroll
                for (int r = 0; r < RB; ++r) {
                    f4 q = *(const f4*)&qv[cur][r * QS + jj];
                    acc[r] += q.x * xv0;
                    acc[r] += q.y * xv1;
                    acc[r] += q.z * xv2;
                    acc[r] += q.w * xv3;
                }
            }
        }

        if (k + 1 < TPB) {
            qwrite(cur ^ 1);      // consume staged regs (vmcnt hidden by phase B)
            __syncthreads();
            cur ^= 1;
        }
    }

    // reduce over h: fold h-pairs within each wave
#pragma unroll
    for (int r = 0; r < RB; ++r)
#pragma unroll
        for (int c = 0; c < 4; ++c)
            acc[r][c] += __shfl_xor(acc[r][c], 32);

    const int w    = t >> 6;
    const int lane = t & 63;
    if (w > 0 && lane < 32) {
#pragma unroll
        for (int r = 0; r < RB; ++r)
            *(f4*)&red[((w - 1) * RB + r) * 128 + d0] = acc[r];
    }
    __syncthreads();
    if (w == 0 && lane < 32) {
#pragma unroll
        for (int r = 0; r < RB; ++r) {
            f4 v = acc[r];
#pragma unroll
            for (int p = 0; p < 3; ++p)
                v += *(const f4*)&red[(p * RB + r) * 128 + d0];
            *(f4*)&ws[(((size_t)js * RG + rg) * RB + r) * DD + d0] = v;
        }
    }
}

// Kernel 2: out[i,:] = PReLU(sum_js partial[js][i,:]) @ W^T + b
__global__ __launch_bounds__(256, 2)
void prelu_linear(const float* __restrict__ alpha,
                  const float* __restrict__ W,
                  const float* __restrict__ b,
                  const float* __restrict__ ws,
                  float* __restrict__ out)
{
    __shared__ float Wt[128 * 129];  // W transposed, padded
    __shared__ float p[16 * 128];    // PReLU'd rows
    const int t  = threadIdx.x;
    const int i0 = blockIdx.x * 16;

    // load W (row-major [dout][k]) transposed into Wt[k][dout]
#pragma unroll
    for (int it = 0; it < 16; ++it) {
        int f  = (it * 256 + t) * 4;
        int d  = f >> 7;
        int kk = f & 127;
        f4 w4 = *(const f4*)(W + f);
        Wt[(kk + 0) * 129 + d] = w4.x;
        Wt[(kk + 1) * 129 + d] = w4.y;
        Wt[(kk + 2) * 129 + d] = w4.z;
        Wt[(kk + 3) * 129 + d] = w4.w;
    }

    // combine 4 partials + PReLU
#pragma unroll
    for (int it = 0; it < 2; ++it) {
        int fi  = it * 256 + t;          // f4 index 0..511
        int row = i0 + (fi >> 5);        // 32 f4 per row
        int dc  = (fi & 31) << 2;
        if (row < NN) {
            size_t base = (size_t)row * DD + dc;
            f4 v = *(const f4*)(ws + base);
            v += *(const f4*)(ws + base + (size_t)1 * RG * RB * DD);
            v += *(const f4*)(ws + base + (size_t)2 * RG * RB * DD);
            v += *(const f4*)(ws + base + (size_t)3 * RG * RB * DD);
            f4 al = *(const f4*)(alpha + dc);
            f4 pv;
            pv.x = v.x >= 0.f ? v.x : al.x * v.x;
            pv.y = v.y >= 0.f ? v.y : al.y * v.y;
            pv.z = v.z >= 0.f ? v.z : al.z * v.z;
            pv.w = v.w >= 0.f ? v.w : al.w * v.w;
            *(f4*)&p[(row - i0) * 128 + dc] = pv;
        }
    }
    __syncthreads();

    const int d  = t & 127;
    const int rq = t >> 7;
    const float bv = b[d];
    float acc[8];
#pragma unroll
    for (int ri = 0; ri < 8; ++ri) acc[ri] = 0.f;
#pragma unroll 8
    for (int k = 0; k < 128; ++k) {
        float wv = Wt[k * 129 + d];
#pragma unroll
        for (int ri = 0; ri < 8; ++ri)
            acc[ri] += p[(rq * 8 + ri) * 128 + k] * wv;
    }
#pragma unroll
    for (int ri = 0; ri < 8; ++ri) {
        int row = i0 + rq * 8 + ri;
        if (row < NN) out[(size_t)row * DD + d] = acc[ri] + bv;
    }
}

extern "C" void kernel_launch(void* const* d_in, const int* in_sizes, int n_in,
                              void* d_out, int out_size, void* d_ws, size_t ws_size,
                              hipStream_t stream) {
    const float* theta = (const float*)d_in[0];
    const float* T     = (const float*)d_in[1];
    const float* x     = (const float*)d_in[2];
    const float* a     = (const float*)d_in[3];
    const float* alpha = (const float*)d_in[4];
    const float* W     = (const float*)d_in[5];
    const float* b     = (const float*)d_in[6];
    float* out = (float*)d_out;
    float* ws  = (float*)d_ws;

    dim3 blk(256);
    dim3 g1(RG * JS);                 // 2500 blocks
    diffuse_spmm<<<g1, blk, 0, stream>>>(theta, T, x, a, ws);

    dim3 g2((NN + 15) / 16);          // 313 blocks
    prelu_linear<<<g2, blk, 0, stream>>>(alpha, W, b, ws, out);
}